// Round 9
// baseline (133.347 us; speedup 1.0000x reference)
//
#include <hip/hip_runtime.h>
#include <math.h>

#define NS     32768             // samples per sequence
#define NB     128               // interpolation bins
#define CELL   32                // samples per thread-cell (32-aligned, never crosses a segment)
#define CPB    32                // cells per part (per head)
#define PART   (CELL * CPB)      // 1024 samples
#define NPARTS (NS / PART)       // 32 parts per sequence
#define TPB    256
#define NBATCH 16
#define GRID   (NBATCH * NPARTS) // 512 blocks — all resident at t=0 (cap ~2048)
#define NBIN   6                 // bins spanned by one part (4 segments + edges)

// sin(2*pi*x): v_sin_f32 takes revolutions; reduce to [-0.5, 0.5] first
__device__ __forceinline__ float sinr(float x) {
    return __builtin_amdgcn_sinf(x - rintf(x));
}

// linear-interp segment params for a 32-aligned cell at sample i
__device__ __forceinline__ void seg_params(int i, int& lo, int& hi,
                                           double& w0, double& wst) {
    if (i < 128)            { lo = 0;   hi = 1;   w0 = 0.0; wst = 0.0; }
    else if (i >= NS - 128) { lo = 127; hi = 127; w0 = 0.0; wst = 0.0; }
    else {
        lo = (i - 128) >> 8;  hi = lo + 1;
        int off = (i - 128) & 255;
        w0 = (off + 0.5) * (1.0 / 256.0);
        wst = 1.0 / 256.0;
    }
}

// bin value for stream q at bin j; phase streams (f0, std, modf) and b are
// pre-scaled to revolutions so all downstream phase math is in revolutions
__device__ __forceinline__ double bin_value(const float* xs, int q, int j) {
    const double PI_    = 3.14159265358979323846;
    const double INV2PI = 0.15915494309189533576888376337251;
    const double MINF   = 40.0 / 11025.0;
    const double FRNG   = (4000.0 - 40.0) / 11025.0;
    if (q == 0) {                                   // amp (unscaled)
        double a0 = (double)xs[j], a1 = (double)xs[NB + j];
        return sqrt(a0 * a0 + a1 * a1);
    }
    double ang = atan2((double)xs[(2 * q - 1) * NB + j],
                       (double)xs[(2 * q - 2) * NB + j]) / PI_;
    double sh, sc;
    if      (q == 1) { sh = MINF; sc = FRNG; }      // f0
    else if (q == 2) { sh = 1.0;  sc = 0.5;  }      // mix (amplitude, unscaled)
    else if (q == 3) { sh = MINF; sc = FRNG; }      // noise_std
    else if (q == 4) { sh = 0.25; sc = 4.75; }      // mod_factor
    else             { sh = 0.1;  sc = 9.9;  }      // b
    double v = sh + ang * sc;
    if (q != 2) v *= INV2PI;
    return v;
}

// ---- single dispatch: totals -> publish -> decoupled lookback -> synth
__global__ __launch_bounds__(TPB)
void fm_one_kernel(const float* __restrict__ xg, const float* __restrict__ ng,
                   double* __restrict__ wspan, int* __restrict__ wflag,
                   float* __restrict__ out) {
    __shared__ double binsA[8][3][NBIN];   // f64: f0, std, modf
    __shared__ float  binsB[8][6][NBIN];   // f32: all 6 streams
    __shared__ double wtot[4][8][3];
    __shared__ double prefL[8][3];

    int bx = blockIdx.x, bb = bx >> 5, p = bx & (NPARTS - 1);
    int tid = threadIdx.x, lane = tid & 63, wid = tid >> 6;
    int h = tid & 7, c = tid >> 3;         // butterfly needs h in lane bits 0..2
    int P = p * PART;
    int b0 = (P - 128) >> 8; if (b0 < 0) b0 = 0;
    int s  = (bb << 3) + h;
    int i0 = P + c * CELL;

    // stage bins: 8 heads x 6 streams x NBIN
    for (int idx = tid; idx < 8 * 6 * NBIN; idx += TPB) {
        int j = idx % NBIN, q = (idx / NBIN) % 6, h2 = idx / (6 * NBIN);
        const float* xs = xg + (size_t)((bb << 3) + h2) * 10 * NB;
        double v = bin_value(xs, q, min(b0 + j, NB - 1));
        binsB[h2][q][j] = (float)v;
        if      (q == 1) binsA[h2][0][j] = v;
        else if (q == 3) binsA[h2][1][j] = v;
        else if (q == 4) binsA[h2][2][j] = v;
    }
    __syncthreads();

    int lo, hi; double w0, wst;
    seg_params(i0, lo, hi, w0, wst);
    int jL = lo - b0, jH = hi - b0;
    double f0L = binsA[h][0][jL], dF0 = binsA[h][0][jH] - f0L;
    double stL = binsA[h][1][jL], dSt = binsA[h][1][jH] - stL;
    double mfL = binsA[h][2][jL], dMf = binsA[h][2][jH] - mfL;

    // closed-form f64 cell totals over 32 samples (S0/S1 in f32: ~1e-8 rev err)
    const float4* nn = reinterpret_cast<const float4*>(ng + (size_t)s * NS + i0);
    float s0 = 0.f, s1 = 0.f;
    #pragma unroll
    for (int q4 = 0; q4 < CELL / 4; ++q4) {
        float4 nv = nn[q4];
        float jd = (float)(q4 * 4);
        s0 += nv.x; s1 = fmaf(jd, nv.x, s1);
        s0 += nv.y; s1 = fmaf(jd + 1.f, nv.y, s1);
        s0 += nv.z; s1 = fmaf(jd + 2.f, nv.z, s1);
        s0 += nv.w; s1 = fmaf(jd + 3.f, nv.w, s1);
    }
    double S0 = (double)s0, S1 = (double)s1;
    double sw = 32.0 * w0 + 496.0 * wst;
    double t3 = 32.0 * f0L + dF0 * sw;
    double t2 = 32.0 * mfL + dMf * sw;
    double t1 = t3 + stL * S0 + dSt * (w0 * S0 + wst * S1);

    // in-part scan: stride-8 wave scan (head lane fixed) + cross-wave combine
    double v1 = t1, v3 = t3, v2 = t2;
    #pragma unroll
    for (int d = 8; d < 64; d <<= 1) {
        double u1 = __shfl_up(v1, d);
        double u3 = __shfl_up(v3, d);
        double u2 = __shfl_up(v2, d);
        if (lane >= d) { v1 += u1; v3 += u3; v2 += u2; }
    }
    if (lane >= 56) { wtot[wid][h][0] = v1; wtot[wid][h][1] = v3; wtot[wid][h][2] = v2; }
    __syncthreads();
    double b1 = 0.0, b3 = 0.0, b2 = 0.0;
    #pragma unroll
    for (int k = 0; k < 3; ++k)
        if (wid > k) { b1 += wtot[k][h][0]; b3 += wtot[k][h][1]; b2 += wtot[k][h][2]; }

    double e1 = b1 + v1 - t1, e3 = b3 + v3 - t3, e2 = b2 + v2 - t2;   // exclusive

    // publish part totals (c==31 holds inclusive end): agent-scope release
    if (tid >= 248) {
        size_t sb = ((size_t)s * NPARTS + p) * 3;
        __hip_atomic_store(&wspan[sb + 0], b1 + v1, __ATOMIC_RELAXED, __HIP_MEMORY_SCOPE_AGENT);
        __hip_atomic_store(&wspan[sb + 1], b3 + v3, __ATOMIC_RELAXED, __HIP_MEMORY_SCOPE_AGENT);
        __hip_atomic_store(&wspan[sb + 2], b2 + v2, __ATOMIC_RELAXED, __HIP_MEMORY_SCOPE_AGENT);
        __hip_atomic_store(&wflag[s * NPARTS + p], 1, __ATOMIC_RELEASE, __HIP_MEMORY_SCOPE_AGENT);
    }

    // decoupled lookback: 24 chains (8h x 3k) x 8 threads, <=4 loads each
    if (tid < 192) {
        int r = tid & 7, g = tid >> 3, k = g % 3, h2 = g / 3;
        int s2 = (bb << 3) + h2;
        const double* sp = wspan + ((size_t)s2 * NPARTS) * 3 + k;
        const int* fp = wflag + s2 * NPARTS;
        double acc = 0.0;
        #pragma unroll
        for (int q = 0; q < NPARTS / 8; ++q) {
            int idx = r + q * 8;
            if (idx < p) {
                while (__hip_atomic_load(&fp[idx], __ATOMIC_ACQUIRE,
                                         __HIP_MEMORY_SCOPE_AGENT) == 0) { }
                acc += __hip_atomic_load(&sp[idx * 3], __ATOMIC_RELAXED,
                                         __HIP_MEMORY_SCOPE_AGENT);
            }
        }
        #pragma unroll
        for (int m = 1; m <= 4; m <<= 1) acc += __shfl_xor(acc, m);
        if (r == 0) prefL[h2][k] = acc;
    }
    __syncthreads();

    // exact f64 anchors -> f32 fractional revolutions
    double a1 = prefL[h][0] + e1;
    double a3 = prefL[h][1] + e3;
    double a2 = prefL[h][2] + e2;
    float fr1 = (float)(a1 - rint(a1));
    float fr3 = (float)(a3 - rint(a3));
    float fr2 = (float)(a2 - rint(a2));

    float amL = binsB[h][0][jL], dAm = binsB[h][0][jH] - amL;
    float g0L = binsB[h][1][jL], gF0 = binsB[h][1][jH] - g0L;
    float mxL = binsB[h][2][jL], dMx = binsB[h][2][jH] - mxL;
    float gsL = binsB[h][3][jL], gSt = binsB[h][3][jH] - gsL;
    float gmL = binsB[h][4][jL], gMf = binsB[h][4][jH] - gmL;
    float bbL = binsB[h][5][jL], dBb = binsB[h][5][jH] - bbL;
    float w0f = (float)w0, wsf = (float)wst;

    float arr[CELL];
    float d1 = 0.f, d2 = 0.f, d3 = 0.f;
    #pragma unroll
    for (int q4 = 0; q4 < CELL / 4; ++q4) {
        float4 nv = nn[q4];                 // L1-hot reload
        float nf[4] = {nv.x, nv.y, nv.z, nv.w};
        #pragma unroll
        for (int u = 0; u < 4; ++u) {
            int j = q4 * 4 + u;
            float wf  = fmaf((float)j, wsf, w0f);
            float f0v = fmaf(wf, gF0, g0L);
            float stv = fmaf(wf, gSt, gsL);
            float mfv = fmaf(wf, gMf, gmL);
            d3 += f0v;                       // cs3 (rev, relative to anchor)
            d1 += fmaf(nf[u], stv, f0v);     // cs1
            d2 += mfv;                       // cs2
            float ampv = fmaf(wf, dAm, amL);
            float mixv = fmaf(wf, dMx, mxL);
            float bv   = fmaf(wf, dBb, bbL);
            float s2 = sinr(fr2 + d2);
            float s1 = sinr(fr1 + d1);
            float s3 = sinr(fmaf(bv, s2, fr3 + d3));
            float harm = ampv * mixv;
            arr[j] = fmaf(harm, s3, (ampv - harm) * s1);
        }
    }

    // head-mean: butterfly over lane bits 0..2
    #pragma unroll
    for (int m = 1; m <= 4; m <<= 1) {
        #pragma unroll
        for (int j = 0; j < CELL; ++j) arr[j] += __shfl_xor(arr[j], m);
    }
    if (h == 0) {
        float4* op = reinterpret_cast<float4*>(out + (size_t)bb * NS + i0);
        #pragma unroll
        for (int j4 = 0; j4 < CELL / 4; ++j4)
            op[j4] = make_float4(arr[j4 * 4 + 0] * 0.125f, arr[j4 * 4 + 1] * 0.125f,
                                 arr[j4 * 4 + 2] * 0.125f, arr[j4 * 4 + 3] * 0.125f);
    }
}

extern "C" void kernel_launch(void* const* d_in, const int* in_sizes, int n_in,
                              void* d_out, int out_size, void* d_ws, size_t ws_size,
                              hipStream_t stream) {
    const float* x     = (const float*)d_in[0];
    const float* noise = (const float*)d_in[1];
    float* out = (float*)d_out;
    // ws: wspan [128 seq][32 part][3] f64 (96 KB) | wflag [128][32] int (16 KB)
    double* wspan = (double*)d_ws;
    int*    wflag = (int*)(wspan + (size_t)128 * NPARTS * 3);
    hipMemsetAsync(wflag, 0, 128 * NPARTS * sizeof(int), stream);
    fm_one_kernel<<<GRID, TPB, 0, stream>>>(x, noise, wspan, wflag, out);
}

// Round 10
// 86.497 us; speedup vs baseline: 1.5416x; 1.5416x over previous
//
#include <hip/hip_runtime.h>
#include <math.h>

#define NS     32768             // samples per sequence
#define NB     128               // interpolation bins
#define CELL   32                // samples per thread-cell (32-aligned, never crosses a segment)
#define CPB    32                // cells per part (per head)
#define PART   (CELL * CPB)      // 1024 samples
#define NPARTS (NS / PART)       // 32 parts per sequence
#define TPB    256
#define NBATCH 16
#define PGRID  (NBATCH * NPARTS) // 512 producer blocks
#define GRID   (2 * PGRID)       // + 512 consumer blocks; all 1024 co-resident
#define NBIN   6                 // bins spanned by one part (4 segments + edges)

// sin(2*pi*x): v_sin_f32 takes revolutions; reduce to [-0.5, 0.5] first
__device__ __forceinline__ float sinr(float x) {
    return __builtin_amdgcn_sinf(x - rintf(x));
}

// linear-interp segment params for a 32-aligned cell at sample i
__device__ __forceinline__ void seg_params(int i, int& lo, int& hi,
                                           double& w0, double& wst) {
    if (i < 128)            { lo = 0;   hi = 1;   w0 = 0.0; wst = 0.0; }
    else if (i >= NS - 128) { lo = 127; hi = 127; w0 = 0.0; wst = 0.0; }
    else {
        lo = (i - 128) >> 8;  hi = lo + 1;
        int off = (i - 128) & 255;
        w0 = (off + 0.5) * (1.0 / 256.0);
        wst = 1.0 / 256.0;
    }
}

// bin value for stream q at bin j; phase streams (f0, std, modf) and b are
// pre-scaled to revolutions so all downstream phase math is in revolutions
__device__ __forceinline__ double bin_value(const float* xs, int q, int j) {
    const double PI_    = 3.14159265358979323846;
    const double INV2PI = 0.15915494309189533576888376337251;
    const double MINF   = 40.0 / 11025.0;
    const double FRNG   = (4000.0 - 40.0) / 11025.0;
    if (q == 0) {                                   // amp (unscaled)
        double a0 = (double)xs[j], a1 = (double)xs[NB + j];
        return sqrt(a0 * a0 + a1 * a1);
    }
    double ang = atan2((double)xs[(2 * q - 1) * NB + j],
                       (double)xs[(2 * q - 2) * NB + j]) / PI_;
    double sh, sc;
    if      (q == 1) { sh = MINF; sc = FRNG; }      // f0
    else if (q == 2) { sh = 1.0;  sc = 0.5;  }      // mix (amplitude, unscaled)
    else if (q == 3) { sh = MINF; sc = FRNG; }      // noise_std
    else if (q == 4) { sh = 0.25; sc = 4.75; }      // mod_factor
    else             { sh = 0.1;  sc = 9.9;  }      // b
    double v = sh + ang * sc;
    if (q != 2) v *= INV2PI;
    return v;
}

// closed-form f64 cell totals over 32 samples; S0/S1 summed in f32 (error
// ~1e-8 rev per cell — far below the f32 synth noise floor)
__device__ __forceinline__ void cell_totals(
        const float4* nn, double f0L, double dF0, double stL, double dSt,
        double mfL, double dMf, double w0, double wst,
        double& t1, double& t3, double& t2) {
    float s0 = 0.f, s1 = 0.f;
    #pragma unroll
    for (int q4 = 0; q4 < CELL / 4; ++q4) {
        float4 nv = nn[q4];
        float jd = (float)(q4 * 4);
        s0 += nv.x; s1 = fmaf(jd, nv.x, s1);
        s0 += nv.y; s1 = fmaf(jd + 1.f, nv.y, s1);
        s0 += nv.z; s1 = fmaf(jd + 2.f, nv.z, s1);
        s0 += nv.w; s1 = fmaf(jd + 3.f, nv.w, s1);
    }
    double S0 = (double)s0, S1 = (double)s1;
    double sw = 32.0 * w0 + 496.0 * wst;            // sum of w over the cell
    t3 = 32.0 * f0L + dF0 * sw;
    t2 = 32.0 * mfL + dMf * sw;
    t1 = t3 + stL * S0 + dSt * (w0 * S0 + wst * S1);
}

__global__ __launch_bounds__(TPB)
void fm_fused_kernel(const float* __restrict__ xg, const float* __restrict__ ng,
                     double* __restrict__ wspan, int* __restrict__ wflag,
                     float* __restrict__ out) {
    __shared__ double binsA[8][3][NBIN];   // f64: f0, std, modf
    __shared__ float  binsB[8][6][NBIN];   // f32: all 6 streams (consumer only)
    __shared__ double wtot[4][8][3];
    __shared__ double prefL[8][3];

    int bx0 = blockIdx.x;
    bool producer = bx0 < PGRID;
    int bx = producer ? bx0 : bx0 - PGRID;
    int bb = bx >> 5, p = bx & (NPARTS - 1);
    int tid = threadIdx.x, lane = tid & 63, wid = tid >> 6;
    int P = p * PART;
    int b0 = (P - 128) >> 8; if (b0 < 0) b0 = 0;

    if (producer) {
        // ---------------- producer: span totals for (bb, p) ----------------
        int h = tid >> 5, c = tid & 31;    // half-wave per head: coalesced
        int s  = (bb << 3) + h;
        int i0 = P + c * CELL;

        if (tid < 144) {                   // 8 heads x 3 streams x 6 bins
            int j = tid % NBIN, r = (tid / NBIN) % 3, h2 = tid / (3 * NBIN);
            int q = (r == 0) ? 1 : (r == 1) ? 3 : 4;
            const float* xs = xg + (size_t)((bb << 3) + h2) * 10 * NB;
            binsA[h2][r][j] = bin_value(xs, q, min(b0 + j, NB - 1));
        }
        __syncthreads();

        int lo, hi; double w0, wst;
        seg_params(i0, lo, hi, w0, wst);
        int jL = lo - b0, jH = hi - b0;
        double f0L = binsA[h][0][jL], dF0 = binsA[h][0][jH] - f0L;
        double stL = binsA[h][1][jL], dSt = binsA[h][1][jH] - stL;
        double mfL = binsA[h][2][jL], dMf = binsA[h][2][jH] - mfL;

        const float4* nn = reinterpret_cast<const float4*>(ng + (size_t)s * NS + i0);
        double t1, t3, t2;
        cell_totals(nn, f0L, dF0, stL, dSt, mfL, dMf, w0, wst, t1, t3, t2);

        double v1 = t1, v3 = t3, v2 = t2;
        #pragma unroll
        for (int d = 1; d < 32; d <<= 1) {
            double u1 = __shfl_up(v1, d);
            double u3 = __shfl_up(v3, d);
            double u2 = __shfl_up(v2, d);
            if ((lane & 31) >= d) { v1 += u1; v3 += u3; v2 += u2; }
        }
        if (c == 31) {
            size_t sb = ((size_t)s * NPARTS + p) * 3;
            __hip_atomic_store(&wspan[sb + 0], v1, __ATOMIC_RELAXED, __HIP_MEMORY_SCOPE_AGENT);
            __hip_atomic_store(&wspan[sb + 1], v3, __ATOMIC_RELAXED, __HIP_MEMORY_SCOPE_AGENT);
            __hip_atomic_store(&wspan[sb + 2], v2, __ATOMIC_RELAXED, __HIP_MEMORY_SCOPE_AGENT);
        }
        __syncthreads();                   // vmcnt(0) drain: data globally done
        if (tid == 0)
            __hip_atomic_store(&wflag[bb * NPARTS + p], 1,
                               __ATOMIC_RELEASE, __HIP_MEMORY_SCOPE_AGENT);
        return;
    }

    // ---------------- consumer: full synth for (bb, p) ----------------
    int h = tid & 7, c = tid >> 3;         // butterfly needs h in lane bits 0..2
    int s  = (bb << 3) + h;
    int i0 = P + c * CELL;

    // stage bins: 8 heads x 6 streams x NBIN (flag-independent)
    for (int idx = tid; idx < 8 * 6 * NBIN; idx += TPB) {
        int j = idx % NBIN, q = (idx / NBIN) % 6, h2 = idx / (6 * NBIN);
        const float* xs = xg + (size_t)((bb << 3) + h2) * 10 * NB;
        double v = bin_value(xs, q, min(b0 + j, NB - 1));
        binsB[h2][q][j] = (float)v;
        if      (q == 1) binsA[h2][0][j] = v;
        else if (q == 3) binsA[h2][1][j] = v;
        else if (q == 4) binsA[h2][2][j] = v;
    }
    __syncthreads();

    int lo, hi; double w0, wst;
    seg_params(i0, lo, hi, w0, wst);
    int jL = lo - b0, jH = hi - b0;
    double f0L = binsA[h][0][jL], dF0 = binsA[h][0][jH] - f0L;
    double stL = binsA[h][1][jL], dSt = binsA[h][1][jH] - stL;
    double mfL = binsA[h][2][jL], dMf = binsA[h][2][jH] - mfL;

    const float4* nn = reinterpret_cast<const float4*>(ng + (size_t)s * NS + i0);
    double t1, t3, t2;
    cell_totals(nn, f0L, dF0, stL, dSt, mfL, dMf, w0, wst, t1, t3, t2);

    // in-part scan: stride-8 wave scan (head lane fixed) + cross-wave combine
    double v1 = t1, v3 = t3, v2 = t2;
    #pragma unroll
    for (int d = 8; d < 64; d <<= 1) {
        double u1 = __shfl_up(v1, d);
        double u3 = __shfl_up(v3, d);
        double u2 = __shfl_up(v2, d);
        if (lane >= d) { v1 += u1; v3 += u3; v2 += u2; }
    }
    if (lane >= 56) { wtot[wid][h][0] = v1; wtot[wid][h][1] = v3; wtot[wid][h][2] = v2; }
    __syncthreads();
    double b1 = 0.0, b3 = 0.0, b2 = 0.0;
    #pragma unroll
    for (int k = 0; k < 3; ++k)
        if (wid > k) { b1 += wtot[k][h][0]; b3 += wtot[k][h][1]; b2 += wtot[k][h][2]; }

    double e1 = b1 + v1 - t1, e3 = b3 + v3 - t3, e2 = b2 + v2 - t2;   // exclusive

    // throttled poll: 32 lanes on 32 distinct flags, s_sleep between polls.
    // Producers (~4 us) normally finish before we reach here -> near-zero wait.
    if (tid < NPARTS) {
        while (__hip_atomic_load(&wflag[bb * NPARTS + tid], __ATOMIC_ACQUIRE,
                                 __HIP_MEMORY_SCOPE_AGENT) == 0)
            __builtin_amdgcn_s_sleep(2);
    }
    __syncthreads();

    // cross-part prefix: 24 chains (8h x 3k) x 8 threads, <=4 loads each
    if (tid < 192) {
        int r = tid & 7, g = tid >> 3, k = g % 3, h2 = g / 3;
        const double* sp = wspan + ((size_t)(((bb << 3) + h2) * NPARTS)) * 3 + k;
        double acc = 0.0;
        #pragma unroll
        for (int q = 0; q < NPARTS / 8; ++q) {
            int idx = r + q * 8;
            if (idx < p)
                acc += __hip_atomic_load(&sp[idx * 3], __ATOMIC_RELAXED,
                                         __HIP_MEMORY_SCOPE_AGENT);
        }
        #pragma unroll
        for (int m = 1; m <= 4; m <<= 1) acc += __shfl_xor(acc, m);
        if (r == 0) prefL[h2][k] = acc;
    }
    __syncthreads();

    // exact f64 anchors -> f32 fractional revolutions
    double a1 = prefL[h][0] + e1;
    double a3 = prefL[h][1] + e3;
    double a2 = prefL[h][2] + e2;
    float fr1 = (float)(a1 - rint(a1));
    float fr3 = (float)(a3 - rint(a3));
    float fr2 = (float)(a2 - rint(a2));

    float amL = binsB[h][0][jL], dAm = binsB[h][0][jH] - amL;
    float g0L = binsB[h][1][jL], gF0 = binsB[h][1][jH] - g0L;
    float mxL = binsB[h][2][jL], dMx = binsB[h][2][jH] - mxL;
    float gsL = binsB[h][3][jL], gSt = binsB[h][3][jH] - gsL;
    float gmL = binsB[h][4][jL], gMf = binsB[h][4][jH] - gmL;
    float bbL = binsB[h][5][jL], dBb = binsB[h][5][jH] - bbL;
    float w0f = (float)w0, wsf = (float)wst;

    float arr[CELL];
    float d1 = 0.f, d2 = 0.f, d3 = 0.f;
    #pragma unroll
    for (int q4 = 0; q4 < CELL / 4; ++q4) {
        float4 nv = nn[q4];                 // L1-hot reload
        float nf[4] = {nv.x, nv.y, nv.z, nv.w};
        #pragma unroll
        for (int u = 0; u < 4; ++u) {
            int j = q4 * 4 + u;
            float wf  = fmaf((float)j, wsf, w0f);
            float f0v = fmaf(wf, gF0, g0L);
            float stv = fmaf(wf, gSt, gsL);
            float mfv = fmaf(wf, gMf, gmL);
            d3 += f0v;                       // cs3 (rev, relative to anchor)
            d1 += fmaf(nf[u], stv, f0v);     // cs1
            d2 += mfv;                       // cs2
            float ampv = fmaf(wf, dAm, amL);
            float mixv = fmaf(wf, dMx, mxL);
            float bv   = fmaf(wf, dBb, bbL);
            float s2 = sinr(fr2 + d2);
            float s1 = sinr(fr1 + d1);
            float s3 = sinr(fmaf(bv, s2, fr3 + d3));
            float harm = ampv * mixv;
            arr[j] = fmaf(harm, s3, (ampv - harm) * s1);
        }
    }

    // head-mean: butterfly over lane bits 0..2
    #pragma unroll
    for (int m = 1; m <= 4; m <<= 1) {
        #pragma unroll
        for (int j = 0; j < CELL; ++j) arr[j] += __shfl_xor(arr[j], m);
    }
    if (h == 0) {
        float4* op = reinterpret_cast<float4*>(out + (size_t)bb * NS + i0);
        #pragma unroll
        for (int j4 = 0; j4 < CELL / 4; ++j4)
            op[j4] = make_float4(arr[j4 * 4 + 0] * 0.125f, arr[j4 * 4 + 1] * 0.125f,
                                 arr[j4 * 4 + 2] * 0.125f, arr[j4 * 4 + 3] * 0.125f);
    }
}

extern "C" void kernel_launch(void* const* d_in, const int* in_sizes, int n_in,
                              void* d_out, int out_size, void* d_ws, size_t ws_size,
                              hipStream_t stream) {
    const float* x     = (const float*)d_in[0];
    const float* noise = (const float*)d_in[1];
    float* out = (float*)d_out;
    // ws: wspan [128 seq][32 part][3] f64 (96 KB) | wflag [16][32] int (2 KB)
    double* wspan = (double*)d_ws;
    int*    wflag = (int*)(wspan + (size_t)128 * NPARTS * 3);
    hipMemsetAsync(wflag, 0, NBATCH * NPARTS * sizeof(int), stream);
    fm_fused_kernel<<<GRID, TPB, 0, stream>>>(x, noise, wspan, wflag, out);
}

// Round 11
// 80.452 us; speedup vs baseline: 1.6575x; 1.0751x over previous
//
#include <hip/hip_runtime.h>
#include <math.h>

#define NS     32768             // samples per sequence
#define NB     128               // interpolation bins
#define CELL   32                // samples per thread-cell (32-aligned, never crosses a segment)
#define CPB    32                // cells per part (per head)
#define PART   (CELL * CPB)      // 1024 samples
#define NPARTS (NS / PART)       // 32 parts per sequence
#define TPB    256
#define NBATCH 16
#define GRID   (NBATCH * NPARTS) // 512 blocks
#define NBIN   6                 // bins spanned by one part (4 segments + edges)

// sin(2*pi*x): v_sin_f32 takes revolutions; reduce to [-0.5, 0.5] first
__device__ __forceinline__ float sinr(float x) {
    return __builtin_amdgcn_sinf(x - rintf(x));
}

// linear-interp segment params for a 32-aligned cell at sample i
__device__ __forceinline__ void seg_params(int i, int& lo, int& hi,
                                           double& w0, double& wst) {
    if (i < 128)            { lo = 0;   hi = 1;   w0 = 0.0; wst = 0.0; }
    else if (i >= NS - 128) { lo = 127; hi = 127; w0 = 0.0; wst = 0.0; }
    else {
        lo = (i - 128) >> 8;  hi = lo + 1;
        int off = (i - 128) & 255;
        w0 = (off + 0.5) * (1.0 / 256.0);
        wst = 1.0 / 256.0;
    }
}

// bin value for stream q at bin j; phase streams (f0, std, modf) and b are
// pre-scaled to revolutions so all downstream phase math is in revolutions
__device__ __forceinline__ double bin_value(const float* xs, int q, int j) {
    const double PI_    = 3.14159265358979323846;
    const double INV2PI = 0.15915494309189533576888376337251;
    const double MINF   = 40.0 / 11025.0;
    const double FRNG   = (4000.0 - 40.0) / 11025.0;
    if (q == 0) {                                   // amp (unscaled)
        double a0 = (double)xs[j], a1 = (double)xs[NB + j];
        return sqrt(a0 * a0 + a1 * a1);
    }
    double ang = atan2((double)xs[(2 * q - 1) * NB + j],
                       (double)xs[(2 * q - 2) * NB + j]) / PI_;
    double sh, sc;
    if      (q == 1) { sh = MINF; sc = FRNG; }      // f0
    else if (q == 2) { sh = 1.0;  sc = 0.5;  }      // mix (amplitude, unscaled)
    else if (q == 3) { sh = MINF; sc = FRNG; }      // noise_std
    else if (q == 4) { sh = 0.25; sc = 4.75; }      // mod_factor
    else             { sh = 0.1;  sc = 9.9;  }      // b
    double v = sh + ang * sc;
    if (q != 2) v *= INV2PI;
    return v;
}

// closed-form f64 cell totals over 32 samples; S0/S1 summed in f32 (error
// ~1e-8 rev per cell — far below the f32 synth noise floor)
__device__ __forceinline__ void cell_totals(
        const float4* nn, double f0L, double dF0, double stL, double dSt,
        double mfL, double dMf, double w0, double wst,
        double& t1, double& t3, double& t2) {
    float s0 = 0.f, s1 = 0.f;
    #pragma unroll
    for (int q4 = 0; q4 < CELL / 4; ++q4) {
        float4 nv = nn[q4];
        float jd = (float)(q4 * 4);
        s0 += nv.x; s1 = fmaf(jd, nv.x, s1);
        s0 += nv.y; s1 = fmaf(jd + 1.f, nv.y, s1);
        s0 += nv.z; s1 = fmaf(jd + 2.f, nv.z, s1);
        s0 += nv.w; s1 = fmaf(jd + 3.f, nv.w, s1);
    }
    double S0 = (double)s0, S1 = (double)s1;
    double sw = 32.0 * w0 + 496.0 * wst;            // sum of w over the cell
    t3 = 32.0 * f0L + dF0 * sw;
    t2 = 32.0 * mfL + dMf * sw;
    t1 = t3 + stL * S0 + dSt * (w0 * S0 + wst * S1);
}

// ---- K1: per-(seq, part) span totals {cs1, cs3, cs2} -> wspan[seq][part][3]
// Layout h = tid>>5: half-wave per head -> coalesced loads, in-half-wave scan.
__global__ __launch_bounds__(TPB)
void span_kernel(const float* __restrict__ xg, const float* __restrict__ ng,
                 double* __restrict__ wspan) {
    __shared__ double binsA[8][3][NBIN];   // f0, std, modf @ bins b0..b0+5

    int bx = blockIdx.x, bb = bx >> 5, p = bx & (NPARTS - 1);
    int tid = threadIdx.x, lane = tid & 63;
    int h = tid >> 5, c = tid & 31;
    int P = p * PART;
    int b0 = (P - 128) >> 8; if (b0 < 0) b0 = 0;
    int s  = (bb << 3) + h;
    int i0 = P + c * CELL;

    if (tid < 144) {                       // 8 heads x 3 streams x 6 bins
        int j = tid % NBIN, r = (tid / NBIN) % 3, h2 = tid / (3 * NBIN);
        int q = (r == 0) ? 1 : (r == 1) ? 3 : 4;
        const float* xs = xg + (size_t)((bb << 3) + h2) * 10 * NB;
        binsA[h2][r][j] = bin_value(xs, q, min(b0 + j, NB - 1));
    }
    __syncthreads();

    int lo, hi; double w0, wst;
    seg_params(i0, lo, hi, w0, wst);
    int jL = lo - b0, jH = hi - b0;
    double f0L = binsA[h][0][jL], dF0 = binsA[h][0][jH] - f0L;
    double stL = binsA[h][1][jL], dSt = binsA[h][1][jH] - stL;
    double mfL = binsA[h][2][jL], dMf = binsA[h][2][jH] - mfL;

    const float4* nn = reinterpret_cast<const float4*>(ng + (size_t)s * NS + i0);
    double t1, t3, t2;
    cell_totals(nn, f0L, dF0, stL, dSt, mfL, dMf, w0, wst, t1, t3, t2);

    // inclusive scan over the 32 cells of this head (within the half-wave)
    double v1 = t1, v3 = t3, v2 = t2;
    #pragma unroll
    for (int d = 1; d < 32; d <<= 1) {
        double u1 = __shfl_up(v1, d);
        double u3 = __shfl_up(v3, d);
        double u2 = __shfl_up(v2, d);
        if ((lane & 31) >= d) { v1 += u1; v3 += u3; v2 += u2; }
    }
    if (c == 31) {
        size_t sb = ((size_t)s * NPARTS + p) * 3;
        wspan[sb + 0] = v1; wspan[sb + 1] = v3; wspan[sb + 2] = v2;
    }
}

// ---- K2: full synth; in-part prefix from own scan, cross-part from wspan
__global__ __launch_bounds__(TPB)
void fm_kernel(const float* __restrict__ xg, const float* __restrict__ ng,
               const double* __restrict__ wspan, float* __restrict__ out) {
    __shared__ double binsA[8][3][NBIN];
    __shared__ float  binsB[8][6][NBIN];
    __shared__ double wtot[4][8][3];
    __shared__ double prefL[8][3];

    int bx = blockIdx.x, bb = bx >> 5, p = bx & (NPARTS - 1);
    int tid = threadIdx.x, lane = tid & 63, wid = tid >> 6;
    int h = tid & 7, c = tid >> 3;         // butterfly needs h in lane bits 0..2
    int P = p * PART;
    int b0 = (P - 128) >> 8; if (b0 < 0) b0 = 0;
    int s  = (bb << 3) + h;
    int i0 = P + c * CELL;

    // cross-part prefix: 24 chains (8h x 3k) x 8 threads, <=4 strided loads each
    if (tid < 192) {
        int r = tid & 7, g = tid >> 3, k = g % 3, h2 = g / 3;
        const double* sp = wspan + ((size_t)(((bb << 3) + h2) * NPARTS)) * 3 + k;
        double acc = 0.0;
        #pragma unroll
        for (int q = 0; q < NPARTS / 8; ++q) {
            int idx = r + q * 8;
            if (idx < p) acc += sp[idx * 3];
        }
        #pragma unroll
        for (int m = 1; m <= 4; m <<= 1) acc += __shfl_xor(acc, m);
        if (r == 0) prefL[h2][k] = acc;
    }
    // stage bins: 8 heads x 6 streams x NBIN
    for (int idx = tid; idx < 8 * 6 * NBIN; idx += TPB) {
        int j = idx % NBIN, q = (idx / NBIN) % 6, h2 = idx / (6 * NBIN);
        const float* xs = xg + (size_t)((bb << 3) + h2) * 10 * NB;
        double v = bin_value(xs, q, min(b0 + j, NB - 1));
        binsB[h2][q][j] = (float)v;
        if      (q == 1) binsA[h2][0][j] = v;
        else if (q == 3) binsA[h2][1][j] = v;
        else if (q == 4) binsA[h2][2][j] = v;
    }
    __syncthreads();

    int lo, hi; double w0, wst;
    seg_params(i0, lo, hi, w0, wst);
    int jL = lo - b0, jH = hi - b0;
    double f0L = binsA[h][0][jL], dF0 = binsA[h][0][jH] - f0L;
    double stL = binsA[h][1][jL], dSt = binsA[h][1][jH] - stL;
    double mfL = binsA[h][2][jL], dMf = binsA[h][2][jH] - mfL;

    const float4* nn = reinterpret_cast<const float4*>(ng + (size_t)s * NS + i0);
    double t1, t3, t2;
    cell_totals(nn, f0L, dF0, stL, dSt, mfL, dMf, w0, wst, t1, t3, t2);

    // in-part scan: stride-8 wave scan (head lane fixed) + cross-wave combine
    double v1 = t1, v3 = t3, v2 = t2;
    #pragma unroll
    for (int d = 8; d < 64; d <<= 1) {
        double u1 = __shfl_up(v1, d);
        double u3 = __shfl_up(v3, d);
        double u2 = __shfl_up(v2, d);
        if (lane >= d) { v1 += u1; v3 += u3; v2 += u2; }
    }
    if (lane >= 56) { wtot[wid][h][0] = v1; wtot[wid][h][1] = v3; wtot[wid][h][2] = v2; }
    __syncthreads();
    double b1 = 0.0, b3 = 0.0, b2 = 0.0;
    #pragma unroll
    for (int k = 0; k < 3; ++k)
        if (wid > k) { b1 += wtot[k][h][0]; b3 += wtot[k][h][1]; b2 += wtot[k][h][2]; }

    // exact f64 anchors -> f32 fractional revolutions
    double a1 = prefL[h][0] + b1 + (v1 - t1);
    double a3 = prefL[h][1] + b3 + (v3 - t3);
    double a2 = prefL[h][2] + b2 + (v2 - t2);
    float fr1 = (float)(a1 - rint(a1));
    float fr3 = (float)(a3 - rint(a3));
    float fr2 = (float)(a2 - rint(a2));

    float amL = binsB[h][0][jL], dAm = binsB[h][0][jH] - amL;
    float g0L = binsB[h][1][jL], gF0 = binsB[h][1][jH] - g0L;
    float mxL = binsB[h][2][jL], dMx = binsB[h][2][jH] - mxL;
    float gsL = binsB[h][3][jL], gSt = binsB[h][3][jH] - gsL;
    float gmL = binsB[h][4][jL], gMf = binsB[h][4][jH] - gmL;
    float bbL = binsB[h][5][jL], dBb = binsB[h][5][jH] - bbL;
    float w0f = (float)w0, wsf = (float)wst;

    float arr[CELL];
    float d1 = 0.f, d2 = 0.f, d3 = 0.f;
    #pragma unroll
    for (int q4 = 0; q4 < CELL / 4; ++q4) {
        float4 nv = nn[q4];                 // L1/L2-hot reload
        float nf[4] = {nv.x, nv.y, nv.z, nv.w};
        #pragma unroll
        for (int u = 0; u < 4; ++u) {
            int j = q4 * 4 + u;
            float wf  = fmaf((float)j, wsf, w0f);
            float f0v = fmaf(wf, gF0, g0L);
            float stv = fmaf(wf, gSt, gsL);
            float mfv = fmaf(wf, gMf, gmL);
            d3 += f0v;                       // cs3 (rev, relative to anchor)
            d1 += fmaf(nf[u], stv, f0v);     // cs1
            d2 += mfv;                       // cs2
            float ampv = fmaf(wf, dAm, amL);
            float mixv = fmaf(wf, dMx, mxL);
            float bv   = fmaf(wf, dBb, bbL);
            float s2 = sinr(fr2 + d2);
            float s1 = sinr(fr1 + d1);
            float s3 = sinr(fmaf(bv, s2, fr3 + d3));
            float harm = ampv * mixv;
            arr[j] = fmaf(harm, s3, (ampv - harm) * s1);
        }
    }

    // head-mean: butterfly over lane bits 0..2
    #pragma unroll
    for (int m = 1; m <= 4; m <<= 1) {
        #pragma unroll
        for (int j = 0; j < CELL; ++j) arr[j] += __shfl_xor(arr[j], m);
    }
    if (h == 0) {
        float4* op = reinterpret_cast<float4*>(out + (size_t)bb * NS + i0);
        #pragma unroll
        for (int j4 = 0; j4 < CELL / 4; ++j4)
            op[j4] = make_float4(arr[j4 * 4 + 0] * 0.125f, arr[j4 * 4 + 1] * 0.125f,
                                 arr[j4 * 4 + 2] * 0.125f, arr[j4 * 4 + 3] * 0.125f);
    }
}

extern "C" void kernel_launch(void* const* d_in, const int* in_sizes, int n_in,
                              void* d_out, int out_size, void* d_ws, size_t ws_size,
                              hipStream_t stream) {
    const float* x     = (const float*)d_in[0];
    const float* noise = (const float*)d_in[1];
    float* out = (float*)d_out;
    double* wspan = (double*)d_ws;   // [128 seq][32 part][3] f64 = 98304 B
    span_kernel<<<GRID, TPB, 0, stream>>>(x, noise, wspan);
    fm_kernel<<<GRID, TPB, 0, stream>>>(x, noise, wspan, out);
}